// Round 2
// baseline (1320.351 us; speedup 1.0000x reference)
//
#include <hip/hip_runtime.h>
#include <hip/hip_bf16.h>
#include <stdint.h>

#define HIDDEN  2048
#define INTER   8192
#define COMPACT 8192
#define NTOK    16384

typedef unsigned short ushort_t;
typedef float  f32x4  __attribute__((ext_vector_type(4)));
typedef __bf16 bf16x8 __attribute__((ext_vector_type(8)));

// fp32 -> bf16 round-to-nearest-even (finite inputs)
__device__ __forceinline__ ushort_t f2bf(float f) {
    uint32_t u = __builtin_bit_cast(uint32_t, f);
    uint32_t lsb = (u >> 16) & 1u;
    u += 0x7fffu + lsb;
    return (ushort_t)(u >> 16);
}

// Async global->LDS, 16B per lane. HW semantics: wave-uniform base + lane*16,
// which matches lds ptr = base + tid*16 with contiguous (unpadded) layout.
__device__ __forceinline__ void async_cp16(const void* g, void* l) {
    __builtin_amdgcn_global_load_lds(
        (__attribute__((address_space(1))) void*)((void*)g),
        (__attribute__((address_space(3))) void*)l,
        16, 0, 0);
}

// ---------------------------------------------------------------------------
// Prepass 1: gather + fp32->bf16.  xc[c,:] = bf16(x[fg[c],:])
// One block per compact row; thread t converts 8 floats.
// ---------------------------------------------------------------------------
__global__ __launch_bounds__(256)
void k_gather_cast(const float* __restrict__ x, const int* __restrict__ fg,
                   ushort_t* __restrict__ xc)
{
    const int c = blockIdx.x;
    const int t = threadIdx.x;            // 256 threads * 8 floats = 2048
    const float4* src = (const float4*)(x + (size_t)fg[c] * HIDDEN) + (t << 1);
    float4 a = src[0], b = src[1];
    union { ushort_t u[8]; uint4 v; } p;
    p.u[0] = f2bf(a.x); p.u[1] = f2bf(a.y); p.u[2] = f2bf(a.z); p.u[3] = f2bf(a.w);
    p.u[4] = f2bf(b.x); p.u[5] = f2bf(b.y); p.u[6] = f2bf(b.z); p.u[7] = f2bf(b.w);
    *((uint4*)(xc + (size_t)c * HIDDEN) + t) = p.v;
}

// ---------------------------------------------------------------------------
// Prepass 2: plain fp32->bf16 cast, 8 elements/thread.
// ---------------------------------------------------------------------------
__global__ __launch_bounds__(256)
void k_cast(const float* __restrict__ src, ushort_t* __restrict__ dst)
{
    const size_t g = (size_t)blockIdx.x * 256 + threadIdx.x;
    const float4* s = (const float4*)src + (g << 1);
    float4 a = s[0], b = s[1];
    union { ushort_t u[8]; uint4 v; } p;
    p.u[0] = f2bf(a.x); p.u[1] = f2bf(a.y); p.u[2] = f2bf(a.z); p.u[3] = f2bf(a.w);
    p.u[4] = f2bf(b.x); p.u[5] = f2bf(b.y); p.u[6] = f2bf(b.z); p.u[7] = f2bf(b.w);
    *((uint4*)dst + g) = p.v;
}

// ---------------------------------------------------------------------------
// Kernel 1: gate/up GEMM + silu-mul.  h[c,i] = silu(xc.Wg) * (xc.Wu)
// NT GEMM, M=COMPACT, N=INTER, K=HIDDEN. 128x128 tile, BK=32, 4 waves.
// ---------------------------------------------------------------------------
__global__ __launch_bounds__(256, 2)
void k_gateup(const ushort_t* __restrict__ xc,
              const ushort_t* __restrict__ Wg,
              const ushort_t* __restrict__ Wu,
              ushort_t* __restrict__ h)
{
    __shared__ __align__(16) ushort_t As[128 * 32];
    __shared__ __align__(16) ushort_t Bg[128 * 32];
    __shared__ __align__(16) ushort_t Bu[128 * 32];

    const int tid = threadIdx.x;
    const int bm0 = blockIdx.y << 7;
    const int bn0 = blockIdx.x << 7;

    const int sr = tid >> 2;
    const int sc = (tid & 3) << 3;

    const ushort_t* pa0 = xc + (size_t)(bm0 + sr) * HIDDEN + sc;
    const ushort_t* pa1 = pa0 + (size_t)64 * HIDDEN;
    const ushort_t* pg0 = Wg + (size_t)(bn0 + sr) * HIDDEN + sc;
    const ushort_t* pg1 = pg0 + (size_t)64 * HIDDEN;
    const ushort_t* pu0 = Wu + (size_t)(bn0 + sr) * HIDDEN + sc;
    const ushort_t* pu1 = pu0 + (size_t)64 * HIDDEN;

    ushort_t* lA0 = &As[tid << 3];
    ushort_t* lA1 = &As[(tid + 256) << 3];
    ushort_t* lG0 = &Bg[tid << 3];
    ushort_t* lG1 = &Bg[(tid + 256) << 3];
    ushort_t* lU0 = &Bu[tid << 3];
    ushort_t* lU1 = &Bu[(tid + 256) << 3];

    const int lane = tid & 63;
    const int wv = tid >> 6;
    const int wm = (wv & 1) << 6;
    const int wn = (wv >> 1) << 6;
    const int lr = lane & 15;
    const int kq = (lane >> 4) << 3;

    f32x4 accg[4][4], accu[4][4];
    #pragma unroll
    for (int i = 0; i < 4; ++i)
        #pragma unroll
        for (int j = 0; j < 4; ++j) {
            accg[i][j] = (f32x4){0.f, 0.f, 0.f, 0.f};
            accu[i][j] = (f32x4){0.f, 0.f, 0.f, 0.f};
        }

    for (int k0 = 0; k0 < HIDDEN; k0 += 32) {
        async_cp16(pa0, lA0); async_cp16(pa1, lA1);
        async_cp16(pg0, lG0); async_cp16(pg1, lG1);
        async_cp16(pu0, lU0); async_cp16(pu1, lU1);
        pa0 += 32; pa1 += 32; pg0 += 32; pg1 += 32; pu0 += 32; pu1 += 32;
        __syncthreads();

        bf16x8 af[4], gf[4], uf[4];
        #pragma unroll
        for (int i = 0; i < 4; ++i) {
            af[i] = *(const bf16x8*)&As[(wm + (i << 4) + lr) * 32 + kq];
            gf[i] = *(const bf16x8*)&Bg[(wn + (i << 4) + lr) * 32 + kq];
            uf[i] = *(const bf16x8*)&Bu[(wn + (i << 4) + lr) * 32 + kq];
        }
        #pragma unroll
        for (int i = 0; i < 4; ++i)
            #pragma unroll
            for (int j = 0; j < 4; ++j) {
                accg[i][j] = __builtin_amdgcn_mfma_f32_16x16x32_bf16(af[i], gf[j], accg[i][j], 0, 0, 0);
                accu[i][j] = __builtin_amdgcn_mfma_f32_16x16x32_bf16(af[i], uf[j], accu[i][j], 0, 0, 0);
            }
        __syncthreads();
    }

    // C/D layout (m89-verified): col = lane&15, row = (lane>>4)*4 + reg.
    const int orow0 = bm0 + wm + ((lane >> 4) << 2);
    const int ocol  = bn0 + wn + lr;
    #pragma unroll
    for (int i = 0; i < 4; ++i)
        #pragma unroll
        for (int j = 0; j < 4; ++j)
            #pragma unroll
            for (int r = 0; r < 4; ++r) {
                float g = accg[i][j][r];
                float u = accu[i][j][r];
                float s = g / (1.0f + __expf(-g));   // silu
                size_t off = (size_t)(orow0 + (i << 4) + r) * INTER + (size_t)(ocol + (j << 4));
                h[off] = f2bf(s * u);
            }
}

// ---------------------------------------------------------------------------
// Kernel 2: down GEMM.  dn[c,hc] = h[c,:] . Wd[hc,:]   (fp32 output)
// NT GEMM, M=COMPACT, N=HIDDEN, K=INTER.
// ---------------------------------------------------------------------------
__global__ __launch_bounds__(256, 2)
void k_down(const ushort_t* __restrict__ hbuf,
            const ushort_t* __restrict__ Wd,
            float* __restrict__ dn)
{
    __shared__ __align__(16) ushort_t As[128 * 32];
    __shared__ __align__(16) ushort_t Bs[128 * 32];

    const int tid = threadIdx.x;
    const int bm0 = blockIdx.y << 7;
    const int bn0 = blockIdx.x << 7;
    const int sr = tid >> 2;
    const int sc = (tid & 3) << 3;

    const ushort_t* pa0 = hbuf + (size_t)(bm0 + sr) * INTER + sc;
    const ushort_t* pa1 = pa0 + (size_t)64 * INTER;
    const ushort_t* pb0 = Wd + (size_t)(bn0 + sr) * INTER + sc;
    const ushort_t* pb1 = pb0 + (size_t)64 * INTER;

    ushort_t* lA0 = &As[tid << 3];
    ushort_t* lA1 = &As[(tid + 256) << 3];
    ushort_t* lB0 = &Bs[tid << 3];
    ushort_t* lB1 = &Bs[(tid + 256) << 3];

    const int lane = tid & 63;
    const int wv = tid >> 6;
    const int wm = (wv & 1) << 6;
    const int wn = (wv >> 1) << 6;
    const int lr = lane & 15;
    const int kq = (lane >> 4) << 3;

    f32x4 acc[4][4];
    #pragma unroll
    for (int i = 0; i < 4; ++i)
        #pragma unroll
        for (int j = 0; j < 4; ++j)
            acc[i][j] = (f32x4){0.f, 0.f, 0.f, 0.f};

    for (int k0 = 0; k0 < INTER; k0 += 32) {
        async_cp16(pa0, lA0); async_cp16(pa1, lA1);
        async_cp16(pb0, lB0); async_cp16(pb1, lB1);
        pa0 += 32; pa1 += 32; pb0 += 32; pb1 += 32;
        __syncthreads();

        bf16x8 af[4], bfr[4];
        #pragma unroll
        for (int i = 0; i < 4; ++i) {
            af[i]  = *(const bf16x8*)&As[(wm + (i << 4) + lr) * 32 + kq];
            bfr[i] = *(const bf16x8*)&Bs[(wn + (i << 4) + lr) * 32 + kq];
        }
        #pragma unroll
        for (int i = 0; i < 4; ++i)
            #pragma unroll
            for (int j = 0; j < 4; ++j)
                acc[i][j] = __builtin_amdgcn_mfma_f32_16x16x32_bf16(af[i], bfr[j], acc[i][j], 0, 0, 0);
        __syncthreads();
    }

    const int orow0 = bm0 + wm + ((lane >> 4) << 2);
    const int ocol  = bn0 + wn + lr;
    #pragma unroll
    for (int i = 0; i < 4; ++i)
        #pragma unroll
        for (int j = 0; j < 4; ++j)
            #pragma unroll
            for (int r = 0; r < 4; ++r) {
                size_t off = (size_t)(orow0 + (i << 4) + r) * HIDDEN + (size_t)(ocol + (j << 4));
                dn[off] = acc[i][j][r];
            }
}

// ---------------------------------------------------------------------------
// Kernel 3: scatter fp32 rows. out[n,:] = dn[sc[n],:]
// One float4 per thread; 2048 cols = 512 float4 per row.
// ---------------------------------------------------------------------------
__global__ __launch_bounds__(256)
void k_scatter(const float4* __restrict__ dn,
               const int* __restrict__ sc,
               float4* __restrict__ out)
{
    const int gid = blockIdx.x * 256 + threadIdx.x;
    const int row = gid >> 9;
    const int ch  = gid & 511;
    const int s = sc[row];
    out[((size_t)row << 9) + ch] = dn[((size_t)s << 9) + ch];
}

// ---------------------------------------------------------------------------
extern "C" void kernel_launch(void* const* d_in, const int* in_sizes, int n_in,
                              void* d_out, int out_size, void* d_ws, size_t ws_size,
                              hipStream_t stream)
{
    (void)in_sizes; (void)n_in; (void)out_size; (void)ws_size;

    const float* x  = (const float*)d_in[0];   // [16384, 2048] fp32
    const float* Wg = (const float*)d_in[1];   // [8192, 2048]  fp32
    const float* Wu = (const float*)d_in[2];   // [8192, 2048]  fp32
    const float* Wd = (const float*)d_in[3];   // [2048, 8192]  fp32
    const int* fg = (const int*)d_in[4];       // [8192]
    const int* sc = (const int*)d_in[5];       // [16384]
    float* out = (float*)d_out;                // [16384, 2048] fp32 (128 MiB)

    // ws layout (bf16 copies + fp32 dn): 192 MiB total
    ushort_t* xc = (ushort_t*)d_ws;                       // 32 MiB
    ushort_t* wg = xc + (size_t)COMPACT * HIDDEN;         // 32 MiB
    ushort_t* wu = wg + (size_t)INTER * HIDDEN;           // 32 MiB
    ushort_t* wd = wu + (size_t)INTER * HIDDEN;           // 32 MiB
    float*    dn = (float*)(wd + (size_t)HIDDEN * INTER); // 64 MiB
    // h [8192*8192] bf16 = 128 MiB lives in d_out (dead until scatter).
    ushort_t* h = (ushort_t*)d_out;

    k_gather_cast<<<COMPACT, 256, 0, stream>>>(x, fg, xc);
    k_cast<<<(INTER * HIDDEN / 8) / 256, 256, 0, stream>>>(Wg, wg);
    k_cast<<<(INTER * HIDDEN / 8) / 256, 256, 0, stream>>>(Wu, wu);
    k_cast<<<(HIDDEN * INTER / 8) / 256, 256, 0, stream>>>(Wd, wd);

    k_gateup<<<dim3(INTER / 128, COMPACT / 128), 256, 0, stream>>>(xc, wg, wu, h);
    k_down<<<dim3(HIDDEN / 128, COMPACT / 128), 256, 0, stream>>>(h, wd, dn);
    k_scatter<<<(NTOK * HIDDEN / 4) / 256, 256, 0, stream>>>(
        (const float4*)dn, sc, (float4*)out);
}